// Round 2
// baseline (433.183 us; speedup 1.0000x reference)
//
#include <hip/hip_runtime.h>
#include <hip/hip_bf16.h>

// ---------------------------------------------------------------------------
// EncoderLayer: B=2 S=2048 D=768 H=12 DK=64 DFF=3072
// fp32 inputs/outputs (per reference); bf16 MFMA compute with fp32 accumulate.
// ---------------------------------------------------------------------------

typedef short short8 __attribute__((ext_vector_type(8)));
typedef float floatx4 __attribute__((ext_vector_type(4)));
typedef unsigned short ushort_t;

#define B_ 2
#define S_ 2048
#define D_ 768
#define H_ 12
#define DK_ 64
#define DFF_ 3072
#define M_ (B_ * S_)          // 4096 rows

__device__ __forceinline__ float bf2f(ushort_t h) {
  union { unsigned int u; float f; } v; v.u = ((unsigned int)h) << 16; return v.f;
}
__device__ __forceinline__ ushort_t f2bf(float f) {
  union { float f; unsigned int u; } v; v.f = f;
  unsigned int u = v.u;
  unsigned int r = (u + 0x7fffu + ((u >> 16) & 1u)) >> 16;
  return (ushort_t)r;
}

// ---------------------------------------------------------------------------
// Transpose fp32 [K][N] -> bf16 [N][K]
// ---------------------------------------------------------------------------
__global__ __launch_bounds__(256) void transpose_f2b(
    const float* __restrict__ in, ushort_t* __restrict__ out, int K, int N) {
  __shared__ ushort_t t[32][33];
  const int nt = blockIdx.x * 32, kt = blockIdx.y * 32;
  const int tx = threadIdx.x, ty = threadIdx.y;  // 32 x 8
#pragma unroll
  for (int i = 0; i < 4; i++)
    t[ty + i * 8][tx] = f2bf(in[(size_t)(kt + ty + i * 8) * N + nt + tx]);
  __syncthreads();
#pragma unroll
  for (int i = 0; i < 4; i++)
    out[(size_t)(nt + ty + i * 8) * K + kt + tx] = t[tx][ty + i * 8];
}

// fp32 -> bf16 elementwise (n % 4 == 0)
__global__ __launch_bounds__(256) void cvt_f2b(
    const float* __restrict__ in, ushort_t* __restrict__ out, int n) {
  const int i = (blockIdx.x * 256 + threadIdx.x) * 4;
  if (i >= n) return;
#pragma unroll
  for (int j = 0; j < 4; j++) out[i + j] = f2bf(in[i + j]);
}

// concat bq|bk|bv (fp32) -> bqkv fp32
__global__ void concat3(const float* __restrict__ a, const float* __restrict__ b,
                        const float* __restrict__ c, float* __restrict__ o, int n) {
  int i = blockIdx.x * 256 + threadIdx.x;
  if (i >= 3 * n) return;
  o[i] = (i < n) ? a[i] : (i < 2 * n ? b[i - n] : c[i - 2 * n]);
}

// ---------------------------------------------------------------------------
// GEMM: C[M][N] = A[M][K] @ Bt[N][K]^T + bias, optional relu.
// A, Bt, C bf16; bias fp32. m97 structure: 128x128 tile, BK=32,
// global_load_lds(16B), 4 waves, 4x4 fragments per wave.
// Requires M%128==0, N%128==0, K%32==0.
// ---------------------------------------------------------------------------
__global__ __launch_bounds__(256) void gemm_bt(
    const ushort_t* __restrict__ A, const ushort_t* __restrict__ Bt,
    const float* __restrict__ bias, ushort_t* __restrict__ C,
    int M, int N, int K, int relu) {
  __shared__ __align__(16) ushort_t Al[128 * 32];
  __shared__ __align__(16) ushort_t Bl[128 * 32];
  const int tid = threadIdx.x;
  const int w = tid >> 6, lane = tid & 63;
  const int wm = w >> 1, wn = w & 1;
  const int lq = lane >> 4, lr = lane & 15;
  const int m0 = blockIdx.y * 128, n0 = blockIdx.x * 128;

  floatx4 acc[4][4];
#pragma unroll
  for (int i = 0; i < 4; i++)
#pragma unroll
    for (int j = 0; j < 4; j++) acc[i][j] = (floatx4){0.f, 0.f, 0.f, 0.f};

  for (int k0 = 0; k0 < K; k0 += 32) {
    __syncthreads();
#pragma unroll
    for (int i = 0; i < 2; i++) {
      const int base = (w * 2 + i) * 512;       // LDS element base (wave-uniform)
      const int e = base + lane * 8;            // this lane's 8 elements
      const int row = e >> 5, col = e & 31;
      __builtin_amdgcn_global_load_lds(
          (const __attribute__((address_space(1))) void*)(A + (size_t)(m0 + row) * K + k0 + col),
          (__attribute__((address_space(3))) void*)(&Al[base]), 16, 0, 0);
      __builtin_amdgcn_global_load_lds(
          (const __attribute__((address_space(1))) void*)(Bt + (size_t)(n0 + row) * K + k0 + col),
          (__attribute__((address_space(3))) void*)(&Bl[base]), 16, 0, 0);
    }
    __syncthreads();

    short8 af[4], bf[4];
#pragma unroll
    for (int i = 0; i < 4; i++)
      af[i] = *(const short8*)&Al[(wm * 64 + i * 16 + lr) * 32 + lq * 8];
#pragma unroll
    for (int j = 0; j < 4; j++)
      bf[j] = *(const short8*)&Bl[(wn * 64 + j * 16 + lr) * 32 + lq * 8];
#pragma unroll
    for (int i = 0; i < 4; i++)
#pragma unroll
      for (int j = 0; j < 4; j++)
        acc[i][j] = __builtin_amdgcn_mfma_f32_16x16x32_bf16(af[i], bf[j], acc[i][j], 0, 0, 0);
  }

#pragma unroll
  for (int i = 0; i < 4; i++) {
    const int m = m0 + wm * 64 + i * 16 + lq * 4;  // + r below
#pragma unroll
    for (int j = 0; j < 4; j++) {
      const int n = n0 + wn * 64 + j * 16 + lr;
      const float bv = bias[n];
#pragma unroll
      for (int r = 0; r < 4; r++) {
        float v = acc[i][j][r] + bv;
        if (relu) v = v > 0.f ? v : 0.f;
        C[(size_t)(m + r) * N + n] = f2bf(v);
      }
    }
  }
}

// ---------------------------------------------------------------------------
// Flash attention. qkv: [B*S][2304] bf16 rows = {q|k|v}, each [H][DK].
// Grid: (S/64, B*H). Block 256 = 4 waves; wave w owns q rows [q0+16w, +16).
// ---------------------------------------------------------------------------
__global__ __launch_bounds__(256) void flash_attn(
    const ushort_t* __restrict__ qkv, const int* __restrict__ mask,
    ushort_t* __restrict__ ctx) {
  __shared__ __align__(16) ushort_t Kl[64 * 72];   // [kpos][d] rows padded to 72
  __shared__ __align__(16) ushort_t Vt[64 * 72];   // [d][kpos] rows padded to 72
  __shared__ __align__(16) ushort_t Pl[4 * 16 * 72]; // per-wave P [16][72]

  const int tid = threadIdx.x;
  const int w = tid >> 6, lane = tid & 63;
  const int lq = lane >> 4, lr = lane & 15;
  const int q0 = blockIdx.x * 64;
  const int bh = blockIdx.y;
  const int b = bh / H_, h = bh % H_;
  const size_t rs = 3 * D_;  // 2304
  const ushort_t* base = qkv + (size_t)(b * S_) * rs + h * DK_;

  // Q fragments (A-layout): row lr, k = lq*8+j (chunk f adds 32)
  short8 qf[2];
  {
    const int q = q0 + w * 16 + lr;
    const ushort_t* src = base + (size_t)q * rs;
    qf[0] = *(const short8*)(src + lq * 8);
    qf[1] = *(const short8*)(src + 32 + lq * 8);
  }

  floatx4 oacc[4];
#pragma unroll
  for (int d = 0; d < 4; d++) oacc[d] = (floatx4){0.f, 0.f, 0.f, 0.f};
  float mi[4], li[4];
#pragma unroll
  for (int r = 0; r < 4; r++) { mi[r] = -1e30f; li[r] = 0.f; }

  for (int k0 = 0; k0 < S_; k0 += 64) {
    __syncthreads();  // previous tile's LDS reads done
    // stage K[64][64] and V^T[64][64]
#pragma unroll
    for (int i = 0; i < 2; i++) {
      const int idx = tid + i * 256;          // 0..511
      const int r = idx >> 3, c = idx & 7;
      const ushort_t* ks = base + D_ + (size_t)(k0 + r) * rs + c * 8;
      *(short8*)&Kl[r * 72 + c * 8] = *(const short8*)ks;
      const ushort_t* vs = base + 2 * D_ + (size_t)(k0 + r) * rs + c * 8;
      short8 vv = *(const short8*)vs;
#pragma unroll
      for (int j = 0; j < 8; j++) Vt[(c * 8 + j) * 72 + r] = (ushort_t)vv[j];
    }
    __syncthreads();

    // scores: S[16 q][64 kp] per wave
    floatx4 sacc[4];
#pragma unroll
    for (int n = 0; n < 4; n++) sacc[n] = (floatx4){0.f, 0.f, 0.f, 0.f};
#pragma unroll
    for (int n = 0; n < 4; n++)
#pragma unroll
      for (int f = 0; f < 2; f++) {
        short8 bfr = *(const short8*)&Kl[(n * 16 + lr) * 72 + f * 32 + lq * 8];
        sacc[n] = __builtin_amdgcn_mfma_f32_16x16x32_bf16(qf[f], bfr, sacc[n], 0, 0, 0);
      }

    // scale + mask (replace with -1e9 where mask==0, matching jnp.where)
#pragma unroll
    for (int n = 0; n < 4; n++)
#pragma unroll
      for (int r = 0; r < 4; r++) {
        const int qg = q0 + w * 16 + lq * 4 + r;
        const int kp = k0 + n * 16 + lr;
        const int mv = mask[(size_t)qg * S_ + kp];
        float s = sacc[n][r] * 0.125f;
        sacc[n][r] = (mv == 0) ? -1e9f : s;
      }

    // online softmax (rows live across 16-lane groups)
    float al[4];
#pragma unroll
    for (int r = 0; r < 4; r++) {
      float m = fmaxf(fmaxf(sacc[0][r], sacc[1][r]), fmaxf(sacc[2][r], sacc[3][r]));
#pragma unroll
      for (int off = 1; off < 16; off <<= 1) m = fmaxf(m, __shfl_xor(m, off));
      const float mn = fmaxf(mi[r], m);
      al[r] = __expf(mi[r] - mn);
      mi[r] = mn;
    }
#pragma unroll
    for (int r = 0; r < 4; r++) {
      float s = 0.f;
#pragma unroll
      for (int n = 0; n < 4; n++) {
        float p = __expf(sacc[n][r] - mi[r]);
        sacc[n][r] = p;
        s += p;
      }
#pragma unroll
      for (int off = 1; off < 16; off <<= 1) s += __shfl_xor(s, off);
      li[r] = li[r] * al[r] + s;
    }
#pragma unroll
    for (int d = 0; d < 4; d++)
#pragma unroll
      for (int r = 0; r < 4; r++) oacc[d][r] *= al[r];

    // P: C-layout -> LDS -> A-layout (per-wave region; same-wave DS ordering)
#pragma unroll
    for (int n = 0; n < 4; n++)
#pragma unroll
      for (int r = 0; r < 4; r++)
        Pl[(w * 16 + lq * 4 + r) * 72 + n * 16 + lr] = f2bf(sacc[n][r]);

    short8 pf[2];
    pf[0] = *(const short8*)&Pl[(w * 16 + lr) * 72 + lq * 8];
    pf[1] = *(const short8*)&Pl[(w * 16 + lr) * 72 + 32 + lq * 8];
#pragma unroll
    for (int d = 0; d < 4; d++)
#pragma unroll
      for (int f = 0; f < 2; f++) {
        short8 vfr = *(const short8*)&Vt[(d * 16 + lr) * 72 + f * 32 + lq * 8];
        oacc[d] = __builtin_amdgcn_mfma_f32_16x16x32_bf16(pf[f], vfr, oacc[d], 0, 0, 0);
      }
  }

  // write ctx [B*S][D] bf16
#pragma unroll
  for (int d = 0; d < 4; d++)
#pragma unroll
    for (int r = 0; r < 4; r++) {
      const int q = q0 + w * 16 + lq * 4 + r;
      ctx[(size_t)(b * S_ + q) * D_ + h * DK_ + d * 16 + lr] = f2bf(oacc[d][r] / li[r]);
    }
}

// ---------------------------------------------------------------------------
// out = alpha * (x+y - mean)/(std_unbiased + eps) + beta, row = 768
// XF: x is fp32 (else bf16). y always bf16. OF: out fp32 (else bf16).
// ---------------------------------------------------------------------------
template <bool XF, bool OF>
__global__ __launch_bounds__(256) void add_ln(
    const void* __restrict__ xv, const ushort_t* __restrict__ y,
    const float* __restrict__ alpha, const float* __restrict__ beta,
    void* __restrict__ outv) {
  const int row = blockIdx.x, tid = threadIdx.x;
  const int w = tid >> 6, lane = tid & 63;
  __shared__ float red[8];
  const ushort_t* yr = y + (size_t)row * D_;
  float v[3];
#pragma unroll
  for (int i = 0; i < 3; i++) {
    const int c = tid + i * 256;
    float xv_;
    if (XF) xv_ = ((const float*)xv)[(size_t)row * D_ + c];
    else    xv_ = bf2f(((const ushort_t*)xv)[(size_t)row * D_ + c]);
    v[i] = xv_ + bf2f(yr[c]);
  }
  float s = v[0] + v[1] + v[2];
#pragma unroll
  for (int off = 1; off < 64; off <<= 1) s += __shfl_xor(s, off);
  if (lane == 0) red[w] = s;
  __syncthreads();
  const float mean = (red[0] + red[1] + red[2] + red[3]) / (float)D_;
  float d = 0.f;
#pragma unroll
  for (int i = 0; i < 3; i++) { const float t = v[i] - mean; d += t * t; }
#pragma unroll
  for (int off = 1; off < 64; off <<= 1) d += __shfl_xor(d, off);
  if (lane == 0) red[4 + w] = d;
  __syncthreads();
  const float var = (red[4] + red[5] + red[6] + red[7]) / (float)(D_ - 1);
  const float inv = 1.f / (sqrtf(var) + 1e-6f);
  const float a = alpha[0] * inv, bt = beta[0];
#pragma unroll
  for (int i = 0; i < 3; i++) {
    const int c = tid + i * 256;
    const float o = a * (v[i] - mean) + bt;
    if (OF) ((float*)outv)[(size_t)row * D_ + c] = o;
    else    ((ushort_t*)outv)[(size_t)row * D_ + c] = f2bf(o);
  }
}

// ---------------------------------------------------------------------------
// launch
// ---------------------------------------------------------------------------
extern "C" void kernel_launch(void* const* d_in, const int* in_sizes, int n_in,
                              void* d_out, int out_size, void* d_ws, size_t ws_size,
                              hipStream_t stream) {
  const float* x   = (const float*)d_in[0];
  const float* wq  = (const float*)d_in[1];
  const float* bq  = (const float*)d_in[2];
  const float* wk  = (const float*)d_in[3];
  const float* bk  = (const float*)d_in[4];
  const float* wv  = (const float*)d_in[5];
  const float* bv  = (const float*)d_in[6];
  const float* wo  = (const float*)d_in[7];
  const float* bo  = (const float*)d_in[8];
  const float* w1  = (const float*)d_in[9];
  const float* b1  = (const float*)d_in[10];
  const float* w2  = (const float*)d_in[11];
  const float* b2  = (const float*)d_in[12];
  const float* a1  = (const float*)d_in[13];
  const float* be1 = (const float*)d_in[14];
  const float* a2  = (const float*)d_in[15];
  const float* be2 = (const float*)d_in[16];
  const int*   msk = (const int*)d_in[17];

  // workspace layout in ushort units; all offsets multiple of 8 (16B aligned)
  const size_t E_xb    = 0;                               // x as bf16 [M][D]
  const size_t E_wTqkv = E_xb    + (size_t)M_ * D_;
  const size_t E_woT   = E_wTqkv + (size_t)3 * D_ * D_;
  const size_t E_w1T   = E_woT   + (size_t)D_ * D_;
  const size_t E_w2T   = E_w1T   + (size_t)DFF_ * D_;
  const size_t E_bqkv  = E_w2T   + (size_t)D_ * DFF_;     // fp32: 2*2304 ushorts
  const size_t E_qkv   = E_bqkv  + (size_t)2 * 3 * D_;
  const size_t E_ctx   = E_qkv   + (size_t)M_ * 3 * D_;
  const size_t E_attn  = E_ctx   + (size_t)M_ * D_;
  const size_t E_x1    = E_attn  + (size_t)M_ * D_;
  const size_t E_h1    = E_x1    + (size_t)M_ * D_;
  const size_t E_ff    = E_h1    + (size_t)M_ * DFF_;
  const size_t E_total = E_ff    + (size_t)M_ * D_;
  if (ws_size < E_total * sizeof(ushort_t)) return;

  ushort_t* ws    = (ushort_t*)d_ws;
  ushort_t* xb    = ws + E_xb;
  ushort_t* wTqkv = ws + E_wTqkv;
  ushort_t* woT   = ws + E_woT;
  ushort_t* w1T   = ws + E_w1T;
  ushort_t* w2T   = ws + E_w2T;
  float*    bqkv  = (float*)(ws + E_bqkv);
  ushort_t* qkv   = ws + E_qkv;
  ushort_t* ctx   = ws + E_ctx;
  ushort_t* attn  = ws + E_attn;
  ushort_t* x1    = ws + E_x1;
  ushort_t* h1    = ws + E_h1;
  ushort_t* ff    = ws + E_ff;

  const dim3 tb(32, 8);
  transpose_f2b<<<dim3(24, 24), tb, 0, stream>>>(wq, wTqkv, D_, D_);
  transpose_f2b<<<dim3(24, 24), tb, 0, stream>>>(wk, wTqkv + (size_t)D_ * D_, D_, D_);
  transpose_f2b<<<dim3(24, 24), tb, 0, stream>>>(wv, wTqkv + (size_t)2 * D_ * D_, D_, D_);
  transpose_f2b<<<dim3(24, 24), tb, 0, stream>>>(wo, woT, D_, D_);
  transpose_f2b<<<dim3(96, 24), tb, 0, stream>>>(w1, w1T, D_, DFF_);   // -> [3072][768]
  transpose_f2b<<<dim3(24, 96), tb, 0, stream>>>(w2, w2T, DFF_, D_);   // -> [768][3072]
  concat3<<<9, 256, 0, stream>>>(bq, bk, bv, bqkv, D_);
  cvt_f2b<<<(M_ * D_ / 4 + 255) / 256, 256, 0, stream>>>(x, xb, M_ * D_);

  gemm_bt<<<dim3(18, 32), 256, 0, stream>>>(xb, wTqkv, bqkv, qkv, M_, 3 * D_, D_, 0);
  flash_attn<<<dim3(S_ / 64, B_ * H_), 256, 0, stream>>>(qkv, msk, ctx);
  gemm_bt<<<dim3(6, 32), 256, 0, stream>>>(ctx, woT, bo, attn, M_, D_, D_, 0);
  add_ln<true, false><<<M_, 256, 0, stream>>>(x, attn, a1, be1, x1);
  gemm_bt<<<dim3(24, 32), 256, 0, stream>>>(x1, w1T, b1, h1, M_, DFF_, D_, 1);
  gemm_bt<<<dim3(6, 32), 256, 0, stream>>>(h1, w2T, b2, ff, M_, D_, DFF_, 0);
  add_ln<false, true><<<M_, 256, 0, stream>>>(x1, ff, a2, be2, d_out);
}

// Round 3
// 401.818 us; speedup vs baseline: 1.0781x; 1.0781x over previous
//
#include <hip/hip_runtime.h>
#include <hip/hip_bf16.h>

// ---------------------------------------------------------------------------
// EncoderLayer: B=2 S=2048 D=768 H=12 DK=64 DFF=3072
// fp32 inputs/outputs; bf16 MFMA compute with fp32 accumulate.
// ---------------------------------------------------------------------------

typedef short short8 __attribute__((ext_vector_type(8)));
typedef float floatx4 __attribute__((ext_vector_type(4)));
typedef unsigned short ushort_t;
typedef ushort_t ushort4_t __attribute__((ext_vector_type(4)));

#define B_ 2
#define S_ 2048
#define D_ 768
#define H_ 12
#define DK_ 64
#define DFF_ 3072
#define M_ (B_ * S_)          // 4096 rows

__device__ __forceinline__ float bf2f(ushort_t h) {
  union { unsigned int u; float f; } v; v.u = ((unsigned int)h) << 16; return v.f;
}
__device__ __forceinline__ ushort_t f2bf(float f) {
  union { float f; unsigned int u; } v; v.f = f;
  unsigned int u = v.u;
  unsigned int r = (u + 0x7fffu + ((u >> 16) & 1u)) >> 16;
  return (ushort_t)r;
}

// ---------------------------------------------------------------------------
// Transpose fp32 [K][N] -> bf16 [N][K]
// ---------------------------------------------------------------------------
__global__ __launch_bounds__(256) void transpose_f2b(
    const float* __restrict__ in, ushort_t* __restrict__ out, int K, int N) {
  __shared__ ushort_t t[32][33];
  const int nt = blockIdx.x * 32, kt = blockIdx.y * 32;
  const int tx = threadIdx.x, ty = threadIdx.y;  // 32 x 8
#pragma unroll
  for (int i = 0; i < 4; i++)
    t[ty + i * 8][tx] = f2bf(in[(size_t)(kt + ty + i * 8) * N + nt + tx]);
  __syncthreads();
#pragma unroll
  for (int i = 0; i < 4; i++)
    out[(size_t)(nt + ty + i * 8) * K + kt + tx] = t[tx][ty + i * 8];
}

// mask int32 [q][kp] -> biasT bf16 [kp][q]: 0 -> -1e9, else 0
__global__ __launch_bounds__(256) void mask_to_biasT(
    const int* __restrict__ mask, ushort_t* __restrict__ biasT) {
  __shared__ ushort_t t[32][33];
  const int kt = blockIdx.x * 32, qt = blockIdx.y * 32;  // kt: kp tile, qt: q tile
  const int tx = threadIdx.x, ty = threadIdx.y;  // 32 x 8
  const ushort_t neg = f2bf(-1e9f);
#pragma unroll
  for (int i = 0; i < 4; i++)
    t[ty + i * 8][tx] = (mask[(size_t)(qt + ty + i * 8) * S_ + kt + tx] == 0) ? neg : (ushort_t)0;
  __syncthreads();
#pragma unroll
  for (int i = 0; i < 4; i++)
    biasT[(size_t)(kt + ty + i * 8) * S_ + qt + tx] = t[tx][ty + i * 8];
}

// fp32 -> bf16 elementwise (n % 4 == 0)
__global__ __launch_bounds__(256) void cvt_f2b(
    const float* __restrict__ in, ushort_t* __restrict__ out, int n) {
  const int i = (blockIdx.x * 256 + threadIdx.x) * 4;
  if (i >= n) return;
#pragma unroll
  for (int j = 0; j < 4; j++) out[i + j] = f2bf(in[i + j]);
}

// concat bq|bk|bv (fp32) -> bqkv fp32
__global__ void concat3(const float* __restrict__ a, const float* __restrict__ b,
                        const float* __restrict__ c, float* __restrict__ o, int n) {
  int i = blockIdx.x * 256 + threadIdx.x;
  if (i >= 3 * n) return;
  o[i] = (i < n) ? a[i] : (i < 2 * n ? b[i - n] : c[i - 2 * n]);
}

// ---------------------------------------------------------------------------
// GEMM: C[M][N] = A[M][K] @ Bt[N][K]^T + bias, optional relu.
// A, Bt, C bf16; bias fp32. BM=128, BN in {128, 64}.
// BN=128: 2x2 waves, 4x4 frags. BN=64: 4x1 waves, 2x4 frags.
// ---------------------------------------------------------------------------
template <int BN>
__global__ __launch_bounds__(256) void gemm_bt_t(
    const ushort_t* __restrict__ A, const ushort_t* __restrict__ Bt,
    const float* __restrict__ bias, ushort_t* __restrict__ C,
    int M, int N, int K, int relu) {
  constexpr int WN = (BN == 128) ? 2 : 1;
  constexpr int WM = 4 / WN;
  constexpr int FI = 128 / WM / 16;
  constexpr int FJ = BN / WN / 16;
  __shared__ __align__(16) ushort_t Al[128 * 32];
  __shared__ __align__(16) ushort_t Bl[BN * 32];
  const int tid = threadIdx.x;
  const int w = tid >> 6, lane = tid & 63;
  const int wm = (WN == 2) ? (w >> 1) : w;
  const int wn = (WN == 2) ? (w & 1) : 0;
  const int lq = lane >> 4, lr = lane & 15;
  const int m0 = blockIdx.y * 128, n0 = blockIdx.x * BN;

  floatx4 acc[FI][FJ];
#pragma unroll
  for (int i = 0; i < FI; i++)
#pragma unroll
    for (int j = 0; j < FJ; j++) acc[i][j] = (floatx4){0.f, 0.f, 0.f, 0.f};

  for (int k0 = 0; k0 < K; k0 += 32) {
    __syncthreads();
#pragma unroll
    for (int i = 0; i < 2; i++) {
      const int base = (w * 2 + i) * 512;
      const int e = base + lane * 8;
      const int row = e >> 5, col = e & 31;
      __builtin_amdgcn_global_load_lds(
          (const __attribute__((address_space(1))) void*)(A + (size_t)(m0 + row) * K + k0 + col),
          (__attribute__((address_space(3))) void*)(&Al[base]), 16, 0, 0);
    }
#pragma unroll
    for (int i = 0; i < BN / 64; i++) {
      const int base = (w * (BN / 64) + i) * 512;
      const int e = base + lane * 8;
      const int row = e >> 5, col = e & 31;
      __builtin_amdgcn_global_load_lds(
          (const __attribute__((address_space(1))) void*)(Bt + (size_t)(n0 + row) * K + k0 + col),
          (__attribute__((address_space(3))) void*)(&Bl[base]), 16, 0, 0);
    }
    __syncthreads();

    short8 af[FI], bf[FJ];
#pragma unroll
    for (int i = 0; i < FI; i++)
      af[i] = *(const short8*)&Al[(wm * (FI * 16) + i * 16 + lr) * 32 + lq * 8];
#pragma unroll
    for (int j = 0; j < FJ; j++)
      bf[j] = *(const short8*)&Bl[(wn * (FJ * 16) + j * 16 + lr) * 32 + lq * 8];
#pragma unroll
    for (int i = 0; i < FI; i++)
#pragma unroll
      for (int j = 0; j < FJ; j++)
        acc[i][j] = __builtin_amdgcn_mfma_f32_16x16x32_bf16(af[i], bf[j], acc[i][j], 0, 0, 0);
  }

#pragma unroll
  for (int i = 0; i < FI; i++) {
    const int m = m0 + wm * (FI * 16) + i * 16 + lq * 4;
#pragma unroll
    for (int j = 0; j < FJ; j++) {
      const int n = n0 + wn * (FJ * 16) + j * 16 + lr;
      const float bv = bias[n];
#pragma unroll
      for (int r = 0; r < 4; r++) {
        float v = acc[i][j][r] + bv;
        if (relu) v = v > 0.f ? v : 0.f;
        C[(size_t)(m + r) * N + n] = f2bf(v);
      }
    }
  }
}

// ---------------------------------------------------------------------------
// Flash attention. qkv: [B*S][2304] bf16 rows = {q|k|v}, each [H][DK].
// biasT: bf16 [kp][q] additive mask bias (0 or -1e9).
// Grid: (S/64, B*H). Block 256 = 4 waves; wave w owns q rows [q0+16w, +16).
// Vt/Pl use XOR chunk swizzle to kill scatter-write bank conflicts.
// ---------------------------------------------------------------------------
__global__ __launch_bounds__(256) void flash_attn(
    const ushort_t* __restrict__ qkv, const ushort_t* __restrict__ biasT,
    ushort_t* __restrict__ ctx) {
  __shared__ __align__(16) ushort_t Kl[64 * 72];     // [kp][d]
  __shared__ __align__(16) ushort_t Vt[64 * 72];     // [d][kp], chunk-swizzled
  __shared__ __align__(16) ushort_t Ml[64 * 72];     // [kp][q-local] bias tile
  __shared__ __align__(16) ushort_t Pl[4 * 16 * 72]; // per-wave P, chunk-swizzled

  const int tid = threadIdx.x;
  const int w = tid >> 6, lane = tid & 63;
  const int lq = lane >> 4, lr = lane & 15;
  const int q0 = blockIdx.x * 64;
  const int bh = blockIdx.y;
  const int b = bh / H_, h = bh % H_;
  const size_t rs = 3 * D_;  // 2304
  const ushort_t* base = qkv + (size_t)(b * S_) * rs + h * DK_;

  // Q fragments (A-layout): row lr, k = f*32 + lq*8 + j
  short8 qf[2];
  {
    const int q = q0 + w * 16 + lr;
    const ushort_t* src = base + (size_t)q * rs;
    qf[0] = *(const short8*)(src + lq * 8);
    qf[1] = *(const short8*)(src + 32 + lq * 8);
  }

  floatx4 oacc[4];
#pragma unroll
  for (int d = 0; d < 4; d++) oacc[d] = (floatx4){0.f, 0.f, 0.f, 0.f};
  float mi[4], li[4];
#pragma unroll
  for (int r = 0; r < 4; r++) { mi[r] = -1e30f; li[r] = 0.f; }

  for (int k0 = 0; k0 < S_; k0 += 64) {
    __syncthreads();  // previous tile's LDS reads done
    // stage K[64][64], swizzled V^T, bias tile [64 kp][64 q]
#pragma unroll
    for (int i = 0; i < 2; i++) {
      const int idx = tid + i * 256;          // 0..511
      const int r = idx >> 3, c = idx & 7;
      *(short8*)&Kl[r * 72 + c * 8] =
          *(const short8*)(base + D_ + (size_t)(k0 + r) * rs + c * 8);
      *(short8*)&Ml[r * 72 + c * 8] =
          *(const short8*)(biasT + (size_t)(k0 + r) * S_ + q0 + c * 8);
      short8 vv = *(const short8*)(base + 2 * D_ + (size_t)(k0 + r) * rs + c * 8);
      const int sw = (r >> 3) ^ c;            // chunk swizzle key
#pragma unroll
      for (int j = 0; j < 8; j++)
        Vt[(c * 8 + j) * 72 + sw * 8 + (r & 7)] = (ushort_t)vv[j];
    }
    __syncthreads();

    // scores: S[16 q][64 kp] per wave
    floatx4 sacc[4];
#pragma unroll
    for (int n = 0; n < 4; n++) sacc[n] = (floatx4){0.f, 0.f, 0.f, 0.f};
#pragma unroll
    for (int n = 0; n < 4; n++)
#pragma unroll
      for (int f = 0; f < 2; f++) {
        short8 bfr = *(const short8*)&Kl[(n * 16 + lr) * 72 + f * 32 + lq * 8];
        sacc[n] = __builtin_amdgcn_mfma_f32_16x16x32_bf16(qf[f], bfr, sacc[n], 0, 0, 0);
      }

    // scale + additive mask bias from LDS (b64 per n)
#pragma unroll
    for (int n = 0; n < 4; n++) {
      const ushort4_t bb = *(const ushort4_t*)&Ml[(n * 16 + lr) * 72 + w * 16 + lq * 4];
#pragma unroll
      for (int r = 0; r < 4; r++)
        sacc[n][r] = sacc[n][r] * 0.125f + bf2f(bb[r]);
    }

    // online softmax (rows live across 16-lane groups)
    float al[4];
#pragma unroll
    for (int r = 0; r < 4; r++) {
      float m = fmaxf(fmaxf(sacc[0][r], sacc[1][r]), fmaxf(sacc[2][r], sacc[3][r]));
#pragma unroll
      for (int off = 1; off < 16; off <<= 1) m = fmaxf(m, __shfl_xor(m, off));
      const float mn = fmaxf(mi[r], m);
      al[r] = __expf(mi[r] - mn);
      mi[r] = mn;
    }
#pragma unroll
    for (int r = 0; r < 4; r++) {
      float s = 0.f;
#pragma unroll
      for (int n = 0; n < 4; n++) {
        float p = __expf(sacc[n][r] - mi[r]);
        sacc[n][r] = p;
        s += p;
      }
#pragma unroll
      for (int off = 1; off < 16; off <<= 1) s += __shfl_xor(s, off);
      li[r] = li[r] * al[r] + s;
    }
#pragma unroll
    for (int d = 0; d < 4; d++)
#pragma unroll
      for (int r = 0; r < 4; r++) oacc[d][r] *= al[r];

    // P: C-layout -> LDS (swizzled) -> A-layout
#pragma unroll
    for (int n = 0; n < 4; n++)
#pragma unroll
      for (int r = 0; r < 4; r++) {
        const int ql = lq * 4 + r;
        const int sw = ((2 * n + (lr >> 3)) ^ (ql & 7)) & 7;
        Pl[w * 1152 + ql * 72 + sw * 8 + (lr & 7)] = f2bf(sacc[n][r]);
      }

    short8 pf[2];
#pragma unroll
    for (int f = 0; f < 2; f++) {
      const int sw = (4 * f + lq) ^ (lr & 7);
      pf[f] = *(const short8*)&Pl[w * 1152 + lr * 72 + sw * 8];
    }
#pragma unroll
    for (int d = 0; d < 4; d++)
#pragma unroll
      for (int f = 0; f < 2; f++) {
        const int sw = (4 * f + lq) ^ ((2 * d + (lr >> 3)) & 7);
        short8 vfr = *(const short8*)&Vt[(d * 16 + lr) * 72 + sw * 8];
        oacc[d] = __builtin_amdgcn_mfma_f32_16x16x32_bf16(pf[f], vfr, oacc[d], 0, 0, 0);
      }
  }

  // write ctx [B*S][D] bf16
#pragma unroll
  for (int d = 0; d < 4; d++)
#pragma unroll
    for (int r = 0; r < 4; r++) {
      const int q = q0 + w * 16 + lq * 4 + r;
      ctx[(size_t)(b * S_ + q) * D_ + h * DK_ + d * 16 + lr] = f2bf(oacc[d][r] / li[r]);
    }
}

// ---------------------------------------------------------------------------
// out = alpha * (x+y - mean)/(std_unbiased + eps) + beta, row = 768
// XF: x is fp32 (else bf16). y always bf16. OF: out fp32 (else bf16).
// ---------------------------------------------------------------------------
template <bool XF, bool OF>
__global__ __launch_bounds__(256) void add_ln(
    const void* __restrict__ xv, const ushort_t* __restrict__ y,
    const float* __restrict__ alpha, const float* __restrict__ beta,
    void* __restrict__ outv) {
  const int row = blockIdx.x, tid = threadIdx.x;
  const int w = tid >> 6, lane = tid & 63;
  __shared__ float red[8];
  const ushort_t* yr = y + (size_t)row * D_;
  float v[3];
#pragma unroll
  for (int i = 0; i < 3; i++) {
    const int c = tid + i * 256;
    float xv_;
    if (XF) xv_ = ((const float*)xv)[(size_t)row * D_ + c];
    else    xv_ = bf2f(((const ushort_t*)xv)[(size_t)row * D_ + c]);
    v[i] = xv_ + bf2f(yr[c]);
  }
  float s = v[0] + v[1] + v[2];
#pragma unroll
  for (int off = 1; off < 64; off <<= 1) s += __shfl_xor(s, off);
  if (lane == 0) red[w] = s;
  __syncthreads();
  const float mean = (red[0] + red[1] + red[2] + red[3]) / (float)D_;
  float d = 0.f;
#pragma unroll
  for (int i = 0; i < 3; i++) { const float t = v[i] - mean; d += t * t; }
#pragma unroll
  for (int off = 1; off < 64; off <<= 1) d += __shfl_xor(d, off);
  if (lane == 0) red[4 + w] = d;
  __syncthreads();
  const float var = (red[4] + red[5] + red[6] + red[7]) / (float)(D_ - 1);
  const float inv = 1.f / (sqrtf(var) + 1e-6f);
  const float a = alpha[0] * inv, bt = beta[0];
#pragma unroll
  for (int i = 0; i < 3; i++) {
    const int c = tid + i * 256;
    const float o = a * (v[i] - mean) + bt;
    if (OF) ((float*)outv)[(size_t)row * D_ + c] = o;
    else    ((ushort_t*)outv)[(size_t)row * D_ + c] = f2bf(o);
  }
}

// ---------------------------------------------------------------------------
// launch
// ---------------------------------------------------------------------------
extern "C" void kernel_launch(void* const* d_in, const int* in_sizes, int n_in,
                              void* d_out, int out_size, void* d_ws, size_t ws_size,
                              hipStream_t stream) {
  const float* x   = (const float*)d_in[0];
  const float* wq  = (const float*)d_in[1];
  const float* bq  = (const float*)d_in[2];
  const float* wk  = (const float*)d_in[3];
  const float* bk  = (const float*)d_in[4];
  const float* wv  = (const float*)d_in[5];
  const float* bv  = (const float*)d_in[6];
  const float* wo  = (const float*)d_in[7];
  const float* bo  = (const float*)d_in[8];
  const float* w1  = (const float*)d_in[9];
  const float* b1  = (const float*)d_in[10];
  const float* w2  = (const float*)d_in[11];
  const float* b2  = (const float*)d_in[12];
  const float* a1  = (const float*)d_in[13];
  const float* be1 = (const float*)d_in[14];
  const float* a2  = (const float*)d_in[15];
  const float* be2 = (const float*)d_in[16];
  const int*   msk = (const int*)d_in[17];

  // workspace layout in ushort units; all offsets multiple of 8 (16B aligned)
  const size_t E_xb    = 0;                               // x as bf16 [M][D]
  const size_t E_wTqkv = E_xb    + (size_t)M_ * D_;
  const size_t E_woT   = E_wTqkv + (size_t)3 * D_ * D_;
  const size_t E_w1T   = E_woT   + (size_t)D_ * D_;
  const size_t E_w2T   = E_w1T   + (size_t)DFF_ * D_;
  const size_t E_bqkv  = E_w2T   + (size_t)D_ * DFF_;     // fp32: 2*2304 ushorts
  const size_t E_qkv   = E_bqkv  + (size_t)2 * 3 * D_;
  const size_t E_ctx   = E_qkv   + (size_t)M_ * 3 * D_;
  const size_t E_attn  = E_ctx   + (size_t)M_ * D_;
  const size_t E_x1    = E_attn  + (size_t)M_ * D_;
  const size_t E_h1    = E_x1    + (size_t)M_ * D_;       // h1 [M][DFF]; biasT shares
  const size_t E_ff    = E_h1    + (size_t)M_ * DFF_;
  const size_t E_total = E_ff    + (size_t)M_ * D_;
  if (ws_size < E_total * sizeof(ushort_t)) return;

  ushort_t* ws    = (ushort_t*)d_ws;
  ushort_t* xb    = ws + E_xb;
  ushort_t* wTqkv = ws + E_wTqkv;
  ushort_t* woT   = ws + E_woT;
  ushort_t* w1T   = ws + E_w1T;
  ushort_t* w2T   = ws + E_w2T;
  float*    bqkv  = (float*)(ws + E_bqkv);
  ushort_t* qkv   = ws + E_qkv;
  ushort_t* ctx   = ws + E_ctx;
  ushort_t* attn  = ws + E_attn;
  ushort_t* x1    = ws + E_x1;
  ushort_t* h1    = ws + E_h1;
  ushort_t* biasT = ws + E_h1;   // overlaps h1: biasT used in flash (before h1 written)
  ushort_t* ff    = ws + E_ff;

  const dim3 tb(32, 8);
  transpose_f2b<<<dim3(24, 24), tb, 0, stream>>>(wq, wTqkv, D_, D_);
  transpose_f2b<<<dim3(24, 24), tb, 0, stream>>>(wk, wTqkv + (size_t)D_ * D_, D_, D_);
  transpose_f2b<<<dim3(24, 24), tb, 0, stream>>>(wv, wTqkv + (size_t)2 * D_ * D_, D_, D_);
  transpose_f2b<<<dim3(24, 24), tb, 0, stream>>>(wo, woT, D_, D_);
  transpose_f2b<<<dim3(96, 24), tb, 0, stream>>>(w1, w1T, D_, DFF_);   // -> [3072][768]
  transpose_f2b<<<dim3(24, 96), tb, 0, stream>>>(w2, w2T, DFF_, D_);   // -> [768][3072]
  mask_to_biasT<<<dim3(64, 64), tb, 0, stream>>>(msk, biasT);
  concat3<<<9, 256, 0, stream>>>(bq, bk, bv, bqkv, D_);
  cvt_f2b<<<(M_ * D_ / 4 + 255) / 256, 256, 0, stream>>>(x, xb, M_ * D_);

  gemm_bt_t<128><<<dim3(18, 32), 256, 0, stream>>>(xb, wTqkv, bqkv, qkv, M_, 3 * D_, D_, 0);
  flash_attn<<<dim3(S_ / 64, B_ * H_), 256, 0, stream>>>(qkv, biasT, ctx);
  gemm_bt_t<64><<<dim3(12, 32), 256, 0, stream>>>(ctx, woT, bo, attn, M_, D_, D_, 0);
  add_ln<true, false><<<M_, 256, 0, stream>>>(x, attn, a1, be1, x1);
  gemm_bt_t<128><<<dim3(24, 32), 256, 0, stream>>>(x1, w1T, b1, h1, M_, DFF_, D_, 1);
  gemm_bt_t<64><<<dim3(12, 32), 256, 0, stream>>>(h1, w2T, b2, ff, M_, D_, DFF_, 0);
  add_ln<false, true><<<M_, 256, 0, stream>>>(x1, ff, a2, be2, d_out);
}